// Round 13
// baseline (116.962 us; speedup 1.0000x reference)
//
#include <hip/hip_runtime.h>

#define NEG 5
#define MM 6
#define NCTX 6
#define NC 36
#define DD 128
#define WPB 4           // waves per block
#define RPW 2           // rows per wave (half-wave per row)
#define RPB (WPB * RPW)
#define DROW 12
#define S_SCALE 4096.0f
#define INV_S (1.0f / 4096.0f)

typedef float v2f __attribute__((ext_vector_type(2)));
typedef float v4f __attribute__((ext_vector_type(4)));

__device__ __forceinline__ int geti(const int4& v, int c) {
    switch (c) { case 0: return v.x; case 1: return v.y; case 2: return v.z; default: return v.w; }
}
__device__ __forceinline__ float getf(const float4& v, int c) {
    switch (c) { case 0: return v.x; case 1: return v.y; case 2: return v.z; default: return v.w; }
}

// ============ w-bag: wbuf[b] = sum_m emb0[w2m[b,m]] * mask ============
__global__ __launch_bounds__(256) void sg_w_kernel(
    const int*   __restrict__ w2m,        // [B,6]
    const float* __restrict__ w2m_mask,   // [B,6]
    const float* __restrict__ emb0,       // [V,128]
    float*       __restrict__ wbuf,       // [B,128]
    int B)
{
    const int lane  = threadIdx.x & 63;
    const int wid   = threadIdx.x >> 6;
    const int sub   = lane >> 5;
    const int slane = lane & 31;
    const int base  = lane & 32;
    const int b     = blockIdx.x * RPB + wid * RPW + sub;
    if (b >= B) return;

    int wi = 0; float wmk = 0.f;
    if (slane < MM)           wi  = w2m[(size_t)b * MM + slane];
    else if (slane < 2 * MM)  wmk = w2m_mask[(size_t)b * MM + (slane - MM)];

    const unsigned long long e0p = (unsigned long long)emb0;
    const unsigned int doff = (unsigned int)slane << 4;   // 4 floats per lane

    // forced-MLP: 6 asm loads, all in flight
    v4f rr[MM]; float mk[MM];
    #pragma unroll
    for (int m = 0; m < MM; ++m) {
        const int idx = __shfl(wi, base + m, 64);
        mk[m]         = __shfl(wmk, base + MM + m, 64);
        const unsigned int voff = ((unsigned int)idx << 9) + doff;  // idx*512B
        asm volatile("global_load_dwordx4 %0, %1, %2"
                     : "=v"(rr[m]) : "v"(voff), "s"(e0p) : "memory");
    }
    asm volatile("s_waitcnt vmcnt(0)" ::: "memory");
    __builtin_amdgcn_sched_barrier(0);

    v4f acc = {0.f, 0.f, 0.f, 0.f};
    #pragma unroll
    for (int m = 0; m < MM; ++m) {
        acc[0] += rr[m][0] * mk[m]; acc[1] += rr[m][1] * mk[m];
        acc[2] += rr[m][2] * mk[m]; acc[3] += rr[m][3] * mk[m];
    }
    *reinterpret_cast<v4f*>(wbuf + (size_t)b * DD + slane * 4) = acc;
}

// ============ emb1 fp32 -> fp8(e4m3, x4096), nontemporal source reads ============
__global__ __launch_bounds__(256) void cvt_fp8_kernel(
    const float* __restrict__ emb1, unsigned int* __restrict__ q, long n4)
{
    const long stride = (long)gridDim.x * 256;
    for (long i = (long)blockIdx.x * 256 + threadIdx.x; i < n4; i += stride) {
        v4f v = __builtin_nontemporal_load(reinterpret_cast<const v4f*>(emb1) + i);
        int r = 0;
        r = __builtin_amdgcn_cvt_pk_fp8_f32(v[0] * S_SCALE, v[1] * S_SCALE, r, false);
        r = __builtin_amdgcn_cvt_pk_fp8_f32(v[2] * S_SCALE, v[3] * S_SCALE, r, true);
        q[i] = (unsigned int)r;
    }
}

// ============ dot kernel: forced-MLP fp8 gathers + streaming wbuf ============
__global__ __launch_bounds__(256) void sg_dot8_kernel(
    const int*   __restrict__ data,
    const int*   __restrict__ c2m,
    const float* __restrict__ c2m_mask,
    const unsigned int* __restrict__ q,   // emb1 fp8, 32 uints/row
    const float* __restrict__ wbuf,       // [B,128]
    float*       __restrict__ out,
    int B)
{
    const int lane  = threadIdx.x & 63;
    const int wid   = threadIdx.x >> 6;
    const int sub   = lane >> 5;
    const int slane = lane & 31;
    const int base  = lane & 32;
    const int b     = blockIdx.x * RPB + wid * RPW + sub;

    float loss = 0.0f;
    if (b < B) {
        int4 ci = {0,0,0,0}; float4 cmk = {0.f,0.f,0.f,0.f};
        int nm = 0;
        if (slane < 9)       ci  = reinterpret_cast<const int4*>(c2m + (size_t)b * NC)[slane];
        else if (slane < 18) cmk = reinterpret_cast<const float4*>(c2m_mask + (size_t)b * NC)[slane - 9];
        if (slane < NEG)     nm  = data[(size_t)b * DROW + 2 + NEG + slane];

        float nmf[NEG];
        #pragma unroll
        for (int n = 0; n < NEG; ++n) nmf[n] = (float)__shfl(nm, base + n, 64);

        const int d0 = slane * 4;
        float4 w = *reinterpret_cast<const float4*>(wbuf + (size_t)b * DD + d0);
        w.x *= INV_S; w.y *= INV_S; w.z *= INV_S; w.w *= INV_S;

        // ---- forced-MLP: all 36 fp8-row gathers in flight via asm volatile ----
        const unsigned long long qp = (unsigned long long)q;
        const unsigned int soff = (unsigned int)slane << 2;
        unsigned int rq[NC];
        #pragma unroll
        for (int t = 0; t < NC; ++t) {
            const int k = t >> 2, c = t & 3;
            const int idx = __shfl(geti(ci, c), base + k, 64);
            const unsigned int voff = ((unsigned int)idx << 7) + soff;  // idx*128B
            asm volatile("global_load_dword %0, %1, %2"
                         : "=v"(rq[t]) : "v"(voff), "s"(qp) : "memory");
        }
        asm volatile("s_waitcnt vmcnt(0)" ::: "memory");
        __builtin_amdgcn_sched_barrier(0);

        // ---- consume: 6 contexts x 6 morphemes ----
        float p[NCTX];
        #pragma unroll
        for (int j = 0; j < NCTX; ++j) {
            float pj = 0.f;
            #pragma unroll
            for (int m = 0; m < MM; ++m) {
                const int t = j * MM + m;
                const int k = t >> 2, c = t & 3;
                const float mk = __shfl(getf(cmk, c), base + 9 + k, 64);
                v2f lo = __builtin_amdgcn_cvt_pk_f32_fp8(rq[t], false);
                v2f hi = __builtin_amdgcn_cvt_pk_f32_fp8(rq[t], true);
                pj += mk * (lo[0] * w.x + lo[1] * w.y + hi[0] * w.z + hi[1] * w.w);
            }
            p[j] = pj;
        }

        #pragma unroll
        for (int j = 0; j < NCTX; ++j) {
            float v = p[j];
            #pragma unroll
            for (int off = 16; off >= 1; off >>= 1) v += __shfl_xor(v, off, 64);
            p[j] = v;
        }
        if (slane == 0) {
            float x = fminf(fmaxf(p[0], -10.0f), 10.0f);
            loss = log1pf(expf(-x));
            #pragma unroll
            for (int n = 0; n < NEG; ++n) {
                float y = fminf(fmaxf(-p[1 + n], -10.0f), 10.0f);
                loss += log1pf(expf(-y)) * nmf[n];
            }
        }
    }
    __shared__ float sacc[RPB];
    if (slane == 0) sacc[wid * RPW + sub] = loss;
    __syncthreads();
    if (threadIdx.x == 0) {
        float s = 0.0f;
        #pragma unroll
        for (int i = 0; i < RPB; ++i) s += sacc[i];
        atomicAdd(out, s);
    }
}

// ============ fallback: fused8 (emb0 fp32 inside), plain loads ============
__global__ __launch_bounds__(256) void sg_fused8_kernel(
    const int*   __restrict__ data,
    const int*   __restrict__ w2m,
    const float* __restrict__ w2m_mask,
    const int*   __restrict__ c2m,
    const float* __restrict__ c2m_mask,
    const float* __restrict__ emb0,
    const unsigned int* __restrict__ q,
    float*       __restrict__ out,
    int B)
{
    const int lane  = threadIdx.x & 63;
    const int wid   = threadIdx.x >> 6;
    const int sub   = lane >> 5;
    const int slane = lane & 31;
    const int base  = lane & 32;
    const int b     = blockIdx.x * RPB + wid * RPW + sub;

    float loss = 0.0f;
    if (b < B) {
        int4 ci = {0,0,0,0}; float4 cmk = {0.f,0.f,0.f,0.f};
        int wi = 0; float wmk = 0.f; int nm = 0;
        if (slane < 9)       ci  = reinterpret_cast<const int4*>(c2m + (size_t)b * NC)[slane];
        else if (slane < 18) cmk = reinterpret_cast<const float4*>(c2m_mask + (size_t)b * NC)[slane - 9];
        else if (slane < 24) wi  = w2m[(size_t)b * MM + (slane - 18)];
        else if (slane < 30) wmk = w2m_mask[(size_t)b * MM + (slane - 24)];
        if (slane < NEG) nm = data[(size_t)b * DROW + 2 + NEG + slane];

        float nmf[NEG];
        #pragma unroll
        for (int n = 0; n < NEG; ++n) nmf[n] = (float)__shfl(nm, base + n, 64);

        const int d0 = slane * 4;
        float4 wr[MM]; float wmks[MM];
        #pragma unroll
        for (int m = 0; m < MM; ++m) {
            const int idx = __shfl(wi, base + 18 + m, 64);
            wmks[m] = __shfl(wmk, base + 24 + m, 64);
            wr[m] = *reinterpret_cast<const float4*>(emb0 + (size_t)idx * DD + d0);
        }
        unsigned int rq[NC];
        #pragma unroll
        for (int t = 0; t < NC; ++t) {
            const int k = t >> 2, c = t & 3;
            const int idx = __shfl(geti(ci, c), base + k, 64);
            rq[t] = q[(size_t)idx * 32 + slane];
        }

        float4 w = {0.f,0.f,0.f,0.f};
        #pragma unroll
        for (int m = 0; m < MM; ++m) {
            w.x += wr[m].x * wmks[m]; w.y += wr[m].y * wmks[m];
            w.z += wr[m].z * wmks[m]; w.w += wr[m].w * wmks[m];
        }
        w.x *= INV_S; w.y *= INV_S; w.z *= INV_S; w.w *= INV_S;

        float p[NCTX];
        #pragma unroll
        for (int j = 0; j < NCTX; ++j) {
            float pj = 0.f;
            #pragma unroll
            for (int m = 0; m < MM; ++m) {
                const int t = j * MM + m;
                const int k = t >> 2, c = t & 3;
                const float mk = __shfl(getf(cmk, c), base + 9 + k, 64);
                v2f lo = __builtin_amdgcn_cvt_pk_f32_fp8(rq[t], false);
                v2f hi = __builtin_amdgcn_cvt_pk_f32_fp8(rq[t], true);
                pj += mk * (lo[0] * w.x + lo[1] * w.y + hi[0] * w.z + hi[1] * w.w);
            }
            p[j] = pj;
        }

        #pragma unroll
        for (int j = 0; j < NCTX; ++j) {
            float v = p[j];
            #pragma unroll
            for (int off = 16; off >= 1; off >>= 1) v += __shfl_xor(v, off, 64);
            p[j] = v;
        }
        if (slane == 0) {
            float x = fminf(fmaxf(p[0], -10.0f), 10.0f);
            loss = log1pf(expf(-x));
            #pragma unroll
            for (int n = 0; n < NEG; ++n) {
                float y = fminf(fmaxf(-p[1 + n], -10.0f), 10.0f);
                loss += log1pf(expf(-y)) * nmf[n];
            }
        }
    }
    __shared__ float sacc[RPB];
    if (slane == 0) sacc[wid * RPW + sub] = loss;
    __syncthreads();
    if (threadIdx.x == 0) {
        float s = 0.0f;
        #pragma unroll
        for (int i = 0; i < RPB; ++i) s += sacc[i];
        atomicAdd(out, s);
    }
}

extern "C" void kernel_launch(void* const* d_in, const int* in_sizes, int n_in,
                              void* d_out, int out_size, void* d_ws, size_t ws_size,
                              hipStream_t stream) {
    const int*   data     = (const int*)  d_in[0];
    const int*   w2m      = (const int*)  d_in[1];
    const float* w2m_mask = (const float*)d_in[2];
    const int*   c2m      = (const int*)  d_in[3];
    const float* c2m_mask = (const float*)d_in[4];
    const float* emb0     = (const float*)d_in[5];
    const float* emb1     = (const float*)d_in[6];
    float* out = (float*)d_out;

    const int B     = in_sizes[1] / MM;
    const int vocab = in_sizes[6] / DD;
    const int blocks = (B + RPB - 1) / RPB;

    (void)hipMemsetAsync(out, 0, sizeof(float), stream);

    const size_t qbytes = (size_t)vocab * DD;
    const size_t wbytes = (size_t)B * DD * sizeof(float);
    const long   n4     = (long)vocab * 32;

    if (ws_size >= qbytes + wbytes) {
        unsigned int* q = (unsigned int*)d_ws;
        float* wbuf = (float*)((char*)d_ws + qbytes);
        sg_w_kernel<<<blocks, 64 * WPB, 0, stream>>>(w2m, w2m_mask, emb0, wbuf, B);
        cvt_fp8_kernel<<<2048, 256, 0, stream>>>(emb1, q, n4);
        sg_dot8_kernel<<<blocks, 64 * WPB, 0, stream>>>(data, c2m, c2m_mask, q, wbuf, out, B);
    } else if (ws_size >= qbytes) {
        unsigned int* q = (unsigned int*)d_ws;
        cvt_fp8_kernel<<<2048, 256, 0, stream>>>(emb1, q, n4);
        sg_fused8_kernel<<<blocks, 64 * WPB, 0, stream>>>(
            data, w2m, w2m_mask, c2m, c2m_mask, emb0, q, out, B);
    }
}